// Round 4
// baseline (253.466 us; speedup 1.0000x reference)
//
#include <hip/hip_runtime.h>
#include <hip/hip_bf16.h>

#define DEVINL __device__ __forceinline__

typedef __attribute__((ext_vector_type(8))) short short8;   // 8 bf16 (4 VGPRs)
typedef __attribute__((ext_vector_type(4))) float f32x4;    // MFMA acc

DEVINL float rcp_f(float x) { return __builtin_amdgcn_rcpf(x); }

// compiler-level memory barrier: forces LDS stores to be emitted and kills
// stale-value forwarding. Within-wave DS ordering is guaranteed by hardware.
#define LDS_FENCE() __asm__ volatile("" ::: "memory")

// quad_perm [1,0,3,2]: swap even/odd lanes (pair 2r <-> 2r+1). VALU pipe.
template<int CTRL>
DEVINL float dpp_mov(float x) {
  return __int_as_float(__builtin_amdgcn_update_dpp(
      0, __float_as_int(x), CTRL, 0xF, 0xF, true));
}
DEVINL float pair_sum(float x) { return x + dpp_mov<0xB1>(x); }

// fp32 -> bf16 hi (round-half-up) + exact fp32 residual
DEVINL short bf_hi(float f, float& rem) {
  unsigned u = __float_as_uint(f);
  unsigned rh = (u + 0x8000u) >> 16;
  rem = f - __uint_as_float(rh << 16);
  return (short)rh;
}
DEVINL short bf_of(float f) {
  return (short)((__float_as_uint(f) + 0x8000u) >> 16);
}
DEVINL void cvt_hilo(float4 fa, float4 fb, short8& h, short8& lo) {
  float rm;
  h[0] = bf_hi(fa.x, rm); lo[0] = bf_of(rm);
  h[1] = bf_hi(fa.y, rm); lo[1] = bf_of(rm);
  h[2] = bf_hi(fa.z, rm); lo[2] = bf_of(rm);
  h[3] = bf_hi(fa.w, rm); lo[3] = bf_of(rm);
  h[4] = bf_hi(fb.x, rm); lo[4] = bf_of(rm);
  h[5] = bf_hi(fb.y, rm); lo[5] = bf_of(rm);
  h[6] = bf_hi(fb.z, rm); lo[6] = bf_of(rm);
  h[7] = bf_hi(fb.w, rm); lo[7] = bf_of(rm);
}
DEVINL f32x4 mfma_bf16(short8 a, short8 b, f32x4 c) {
  return __builtin_amdgcn_mfma_f32_16x16x32_bf16(a, b, c, 0, 0, 0);
}

// ================= kernel A: Gram via MFMA, store C to workspace ============
// W layout: W[mol][c][l] = C[mol][row l][cols 4c..4c+3]  (float4 units).
// Stores: per c, 32 lanes x 16B contiguous per group -> fully coalesced.
__global__ __launch_bounds__(256) void gram_kernel(
    const float* __restrict__ A, float* __restrict__ W, int M) {
  const int lane = threadIdx.x & 63;
  const int wave = threadIdx.x >> 6;
  const int q    = lane >> 4;            // Gram: 8-feature sub-chunk
  const int t    = lane & 15;            // Gram: MFMA row index
  const int a    = lane >> 5;            // mol within wave
  const int l    = lane & 31;            // row for readback
  const int molbase = blockIdx.x * 8 + wave * 2;
  if (molbase >= M) return;              // M % 8 == 0

  __shared__ float ldsT[4][2][32 * 36 + 8];

  #pragma unroll 1
  for (int g = 0; g < 2; ++g) {
    const float* Am = A + (size_t)(molbase + g) * (32 * 128);
    f32x4 acc00 = {0.f, 0.f, 0.f, 0.f}, acc01 = {0.f, 0.f, 0.f, 0.f};
    f32x4 acc10 = {0.f, 0.f, 0.f, 0.f}, acc11 = {0.f, 0.f, 0.f, 0.f};
    #pragma unroll
    for (int c = 0; c < 4; ++c) {        // K chunks of 32 features
      const float* pr0 = Am + t * 128        + 32 * c + 8 * q;
      const float* pr1 = Am + (t + 16) * 128 + 32 * c + 8 * q;
      float4 fa0 = *(const float4*)(pr0);
      float4 fb0 = *(const float4*)(pr0 + 4);
      float4 fa1 = *(const float4*)(pr1);
      float4 fb1 = *(const float4*)(pr1 + 4);
      short8 h0, l0, h1, l1;
      cvt_hilo(fa0, fb0, h0, l0);
      cvt_hilo(fa1, fb1, h1, l1);
      // C = (hi+lo)(hi+lo)^T ~= hi hi^T + hi lo^T + lo hi^T  (drop lo lo^T)
      acc00 = mfma_bf16(h0, h0, acc00); acc00 = mfma_bf16(h0, l0, acc00); acc00 = mfma_bf16(l0, h0, acc00);
      acc01 = mfma_bf16(h0, h1, acc01); acc01 = mfma_bf16(h0, l1, acc01); acc01 = mfma_bf16(l0, h1, acc01);
      acc10 = mfma_bf16(h1, h0, acc10); acc10 = mfma_bf16(h1, l0, acc10); acc10 = mfma_bf16(l1, h0, acc10);
      acc11 = mfma_bf16(h1, h1, acc11); acc11 = mfma_bf16(h1, l1, acc11); acc11 = mfma_bf16(l1, h1, acc11);
    }
    // C/D layout: col = lane&15, row = (lane>>4)*4 + reg  [HW-verified]
    float* tg = &ldsT[wave][g][0];
    #pragma unroll
    for (int reg = 0; reg < 4; ++reg) {
      tg[(4 * q + reg) * 36 + t]           = acc00[reg];
      tg[(4 * q + reg) * 36 + 16 + t]      = acc01[reg];
      tg[(16 + 4 * q + reg) * 36 + t]      = acc10[reg];
      tg[(16 + 4 * q + reg) * 36 + 16 + t] = acc11[reg];
    }
  }
  LDS_FENCE();

  const float* tq = &ldsT[wave][a][0];
  float* Wm = W + (size_t)(molbase + a) * 1024;   // 8*32*4 floats per mol
  #pragma unroll
  for (int c = 0; c < 8; ++c) {
    float4 x = *(const float4*)(tq + l * 36 + 4 * c);
    *(float4*)(Wm + (c * 32 + l) * 4) = x;
  }
}

// ================= kernel B: Householder, 1 molecule per wave ===============
// lane = 2*row + h: lane owns C[row][16h .. 16h+15] in r[16].
// Pair lanes (2r, 2r+1) hold complementary column halves -> every reduction is
// a 16-wide local partial + ONE quad_perm xor1 DPP add.
// vbuf/pbuf hold masked x / raw p (indexed by row); frozen entries are zero
// in vbuf, so frozen-column junk is always multiplied by zero (R3-proven).
template<int K>
DEVINL void house_step(float (&r)[16], int row, int h,
                       float* vbuf, float* pbuf, float* de) {
  constexpr int HK = K >> 4, EK = K & 15;           // owner chunk/elem of col K
  constexpr int HP = (K + 1) >> 4, PE = (K + 1) & 15;
  constexpr int PC = PE >> 2, PEE = PE & 3;         // pivot chunk/elem

  float xm = (row > K) ? r[EK] : 0.0f;              // masked column K
  if (h == HK) vbuf[row] = xm;                      // stage RAW x
  LDS_FENCE();

  float4 vc[4];                                     // x on MY column chunk
  #pragma unroll
  for (int j = 0; j < 4; ++j) vc[j] = *(const float4*)(vbuf + 16 * h + 4 * j);
  float x_me = vbuf[row];                           // x at my row (2-way bcast)
  float x0   = vbuf[K + 1];                         // pivot (uniform bcast)

  float n0 = 0.f, n1 = 0.f;
  #pragma unroll
  for (int j = 0; j < 4; ++j) {
    n0 = fmaf(vc[j].x, vc[j].x, n0); n1 = fmaf(vc[j].y, vc[j].y, n1);
    n0 = fmaf(vc[j].z, vc[j].z, n0); n1 = fmaf(vc[j].w, vc[j].w, n1);
  }
  float nn = pair_sum(n0 + n1);

  float alpha = -copysignf(sqrtf(nn), x0);          // new subdiagonal e_K
  float denom = nn - alpha * x0;                    // >= 0
  float beta  = (denom > 1e-20f) ? rcp_f(denom) : 0.0f;   // 2 / v'v
  float v_me  = x_me - ((row == K + 1) ? alpha : 0.0f);   // 0 for frozen rows

  if (h == HP) {                                    // v = x - alpha*e_{K+1}
    if constexpr (PEE == 0)      vc[PC].x -= alpha;
    else if constexpr (PEE == 1) vc[PC].y -= alpha;
    else if constexpr (PEE == 2) vc[PC].z -= alpha;
    else                         vc[PC].w -= alpha;
  }

  float a0 = 0.f, a1 = 0.f;                         // p_row = row . v
  #pragma unroll
  for (int j = 0; j < 4; ++j) {
    a0 = fmaf(r[4 * j + 0], vc[j].x, a0); a1 = fmaf(r[4 * j + 1], vc[j].y, a1);
    a0 = fmaf(r[4 * j + 2], vc[j].z, a0); a1 = fmaf(r[4 * j + 3], vc[j].w, a1);
  }
  float p_me = pair_sum(a0 + a1);
  if (h == 0) pbuf[row] = p_me;                     // stage raw p = C*v
  LDS_FENCE();

  float bv = beta * v_me;                           // auto-0 for frozen rows
  float bp = (row > K) ? beta * p_me : 0.0f;        // mask junk p

  // pass1: read p chunk; apply -bv*p[j] - bp*v[j]; accumulate G = v'p locally
  float g0 = 0.f, g1 = 0.f;
  #pragma unroll
  for (int j = 0; j < 4; ++j) {
    float4 pcx = *(const float4*)(pbuf + 16 * h + 4 * j);
    g0 = fmaf(vc[j].x, pcx.x, g0); g1 = fmaf(vc[j].y, pcx.y, g1);
    g0 = fmaf(vc[j].z, pcx.z, g0); g1 = fmaf(vc[j].w, pcx.w, g1);
    r[4 * j + 0] -= bv * pcx.x + bp * vc[j].x;
    r[4 * j + 1] -= bv * pcx.y + bp * vc[j].y;
    r[4 * j + 2] -= bv * pcx.z + bp * vc[j].z;
    r[4 * j + 3] -= bv * pcx.w + bp * vc[j].w;
  }
  float G  = pair_sum(g0 + g1);                     // junk killed by zero v
  float tv = (beta * beta * G) * v_me;              // auto-0 for frozen rows

  // pass2: + (b^2 G) v_row * v[j]
  #pragma unroll
  for (int j = 0; j < 4; ++j) {
    r[4 * j + 0] = fmaf(tv, vc[j].x, r[4 * j + 0]);
    r[4 * j + 1] = fmaf(tv, vc[j].y, r[4 * j + 1]);
    r[4 * j + 2] = fmaf(tv, vc[j].z, r[4 * j + 2]);
    r[4 * j + 3] = fmaf(tv, vc[j].w, r[4 * j + 3]);
  }

  if (row == K && h == HK) { de[K] = r[EK]; de[32 + K] = alpha; }
}

template<int K>
DEVINL void house_all(float (&r)[16], int row, int h,
                      float* vbuf, float* pbuf, float* de) {
  house_step<K>(r, row, h, vbuf, pbuf, de);
  if constexpr (K < 30) house_all<K + 1>(r, row, h, vbuf, pbuf, de);
}

__global__ __launch_bounds__(256) void house_kernel(
    const float* __restrict__ W, float* __restrict__ DE, int M) {
  const int lane = threadIdx.x & 63;
  const int wave = threadIdx.x >> 6;
  const int row  = lane >> 1;
  const int h    = lane & 1;
  const int mol  = blockIdx.x * 4 + wave;
  if (mol >= M) return;                  // M % 4 == 0

  // per-wave scratch: 72 floats (x | p, +8 pad) -> waves staggered by 8 banks
  __shared__ float sc[4][72];
  float* vbuf = &sc[wave][0];
  float* pbuf = &sc[wave][36];

  // load my half-row: fully coalesced (even lanes 512B dense, odd lanes 512B)
  const float* Wm = W + (size_t)mol * 1024;
  float r[16];
  #pragma unroll
  for (int j = 0; j < 4; ++j) {
    float4 x = *(const float4*)(Wm + ((4 * h + j) * 32 + row) * 4);
    r[4 * j + 0] = x.x; r[4 * j + 1] = x.y;
    r[4 * j + 2] = x.z; r[4 * j + 3] = x.w;
  }

  float* de = DE + (size_t)mol * 64;     // d[0..31] | e[0..31]
  house_all<0>(r, row, h, vbuf, pbuf, de);
  if (row == 31 && h == 1) { de[31] = r[15]; de[63] = 0.0f; }
}

// ================= kernel C: Sturm bisection (R3-proven) ====================
__global__ __launch_bounds__(256) void sturm_kernel(
    const float* __restrict__ DE, float* __restrict__ out, int M) {
  const int lane = threadIdx.x & 63;
  const int wave = threadIdx.x >> 6;
  const int a = lane >> 5, l = lane & 31;
  const int mol = blockIdx.x * 8 + wave * 2 + a;
  if (mol >= M) return;                  // M % 8 == 0

  const float* dm = DE + (size_t)mol * 64;
  float vd[32], ve[32];
  #pragma unroll
  for (int c = 0; c < 8; ++c) {
    float4 dc = *(const float4*)(dm + 4 * c);
    float4 ec = *(const float4*)(dm + 32 + 4 * c);
    vd[4 * c + 0] = dc.x; vd[4 * c + 1] = dc.y;
    vd[4 * c + 2] = dc.z; vd[4 * c + 3] = dc.w;
    ve[4 * c + 0] = ec.x; ve[4 * c + 1] = ec.y;
    ve[4 * c + 2] = ec.z; ve[4 * c + 3] = ec.w;
  }
  // Gershgorin bracket computed locally per lane. ve[31] == 0.
  float glo = vd[0] - fabsf(ve[0]);
  float ghi = vd[0] + fabsf(ve[0]);
  #pragma unroll
  for (int i = 1; i < 32; ++i) {
    float rad = fabsf(ve[i]) + fabsf(ve[i - 1]);
    glo = fminf(glo, vd[i] - rad);
    ghi = fmaxf(ghi, vd[i] + rad);
  }
  float lo = fmaxf(glo - 1e-3f, 0.0f);   // C = A A' is PSD
  float hi = ghi + 1e-3f;

  #pragma unroll
  for (int i = 0; i < 32; ++i) ve[i] *= ve[i];

  // 32 sigma points / round, 3 rounds
  #pragma unroll
  for (int rr = 0; rr < 3; ++rr) {
    float stp = (hi - lo) * (1.0f / 33.0f);
    float sig = fmaf(stp, (float)(l + 1), lo);
    float qq = vd[0] - sig;
    int cnt = (qq < 0.0f) ? 1 : 0;
    #pragma unroll
    for (int i = 1; i < 32; ++i) {
      float qs = (fabsf(qq) < 1e-12f) ? ((qq < 0.0f) ? -1e-12f : 1e-12f) : qq;
      qq = (vd[i] - sig) - ve[i - 1] * rcp_f(qs);
      cnt += (qq < 0.0f) ? 1 : 0;
    }
    unsigned long long m64 = __ballot(cnt >= 1);
    unsigned hm = (unsigned)(m64 >> (a * 32));
    int b = (hm == 0u) ? 32 : (__ffs(hm) - 1);
    float nhi = (b == 32) ? hi : fmaf(stp, (float)(b + 1), lo);
    lo = fmaf(stp, (float)b, lo);
    hi = nhi;
  }

  if (l == 0) out[mol] = 0.5f * (lo + hi);
}

extern "C" void kernel_launch(void* const* d_in, const int* in_sizes, int n_in,
                              void* d_out, int out_size, void* d_ws, size_t ws_size,
                              hipStream_t stream) {
  const float* A = (const float*)d_in[0];
  float* out = (float*)d_out;
  int n_atoms = in_sizes[1];          // 262144
  int M = n_atoms / 32;               // 8192 molecules
  float* W  = (float*)d_ws;           // M * 1024 floats (32.0 MB)
  float* DE = W + (size_t)M * 1024;   // M * 64 floats   (2.0 MB)
  hipLaunchKernelGGL(gram_kernel,  dim3(M / 8), dim3(256), 0, stream, A, W, M);
  hipLaunchKernelGGL(house_kernel, dim3(M / 4), dim3(256), 0, stream, W, DE, M);
  hipLaunchKernelGGL(sturm_kernel, dim3(M / 8), dim3(256), 0, stream, DE, out, M);
}

// Round 5
// 228.268 us; speedup vs baseline: 1.1104x; 1.1104x over previous
//
#include <hip/hip_runtime.h>
#include <hip/hip_bf16.h>

#define DEVINL __device__ __forceinline__

typedef __attribute__((ext_vector_type(8))) short short8;   // 8 bf16 (4 VGPRs)
typedef __attribute__((ext_vector_type(4))) float f32x4;    // MFMA acc

DEVINL float rcp_f(float x) { return __builtin_amdgcn_rcpf(x); }

// compiler-level memory barrier: forces LDS stores to be emitted and kills
// stale-value forwarding. Within-wave DS ordering is guaranteed by hardware;
// all LDS traffic here is wave-private, so no __syncthreads needed.
#define LDS_FENCE() __asm__ volatile("" ::: "memory")

// quad_perm [1,0,3,2]: swap even/odd lanes (pair 2r <-> 2r+1). VALU pipe.
template<int CTRL>
DEVINL float dpp_mov(float x) {
  return __int_as_float(__builtin_amdgcn_update_dpp(
      0, __float_as_int(x), CTRL, 0xF, 0xF, true));
}
DEVINL float pair_sum(float x) { return x + dpp_mov<0xB1>(x); }

// fp32 -> bf16 hi (round-half-up) + exact fp32 residual
DEVINL short bf_hi(float f, float& rem) {
  unsigned u = __float_as_uint(f);
  unsigned rh = (u + 0x8000u) >> 16;
  rem = f - __uint_as_float(rh << 16);
  return (short)rh;
}
DEVINL short bf_of(float f) {
  return (short)((__float_as_uint(f) + 0x8000u) >> 16);
}
DEVINL void cvt_hilo(float4 fa, float4 fb, short8& h, short8& lo) {
  float rm;
  h[0] = bf_hi(fa.x, rm); lo[0] = bf_of(rm);
  h[1] = bf_hi(fa.y, rm); lo[1] = bf_of(rm);
  h[2] = bf_hi(fa.z, rm); lo[2] = bf_of(rm);
  h[3] = bf_hi(fa.w, rm); lo[3] = bf_of(rm);
  h[4] = bf_hi(fb.x, rm); lo[4] = bf_of(rm);
  h[5] = bf_hi(fb.y, rm); lo[5] = bf_of(rm);
  h[6] = bf_hi(fb.z, rm); lo[6] = bf_of(rm);
  h[7] = bf_hi(fb.w, rm); lo[7] = bf_of(rm);
}
DEVINL f32x4 mfma_bf16(short8 a, short8 b, f32x4 c) {
  return __builtin_amdgcn_mfma_f32_16x16x32_bf16(a, b, c, 0, 0, 0);
}

// ---------- Householder step at compile-time pivot K (R4-proven) ------------
// lane = 2*row + h: lane owns C[row][16h .. 16h+15] in r[16]. Pair lanes hold
// complementary column halves -> every reduction is a 16-wide local partial +
// ONE quad_perm xor1 DPP add. vbuf/pbuf hold masked x / raw p (indexed by
// row); frozen entries are zero in vbuf, so frozen-column junk is always
// multiplied by zero.
template<int K>
DEVINL void house_step(float (&r)[16], int row, int h,
                       float* vbuf, float* pbuf, float* de) {
  constexpr int HK = K >> 4, EK = K & 15;           // owner chunk/elem of col K
  constexpr int HP = (K + 1) >> 4, PE = (K + 1) & 15;
  constexpr int PC = PE >> 2, PEE = PE & 3;         // pivot chunk/elem

  float xm = (row > K) ? r[EK] : 0.0f;              // masked column K
  if (h == HK) vbuf[row] = xm;                      // stage RAW x
  LDS_FENCE();

  float4 vc[4];                                     // x on MY column chunk
  #pragma unroll
  for (int j = 0; j < 4; ++j) vc[j] = *(const float4*)(vbuf + 16 * h + 4 * j);
  float x_me = vbuf[row];                           // x at my row (2-way bcast)
  float x0   = vbuf[K + 1];                         // pivot (uniform bcast)

  float n0 = 0.f, n1 = 0.f;
  #pragma unroll
  for (int j = 0; j < 4; ++j) {
    n0 = fmaf(vc[j].x, vc[j].x, n0); n1 = fmaf(vc[j].y, vc[j].y, n1);
    n0 = fmaf(vc[j].z, vc[j].z, n0); n1 = fmaf(vc[j].w, vc[j].w, n1);
  }
  float nn = pair_sum(n0 + n1);

  float alpha = -copysignf(sqrtf(nn), x0);          // new subdiagonal e_K
  float denom = nn - alpha * x0;                    // >= 0
  float beta  = (denom > 1e-20f) ? rcp_f(denom) : 0.0f;   // 2 / v'v
  float v_me  = x_me - ((row == K + 1) ? alpha : 0.0f);   // 0 for frozen rows

  if (h == HP) {                                    // v = x - alpha*e_{K+1}
    if constexpr (PEE == 0)      vc[PC].x -= alpha;
    else if constexpr (PEE == 1) vc[PC].y -= alpha;
    else if constexpr (PEE == 2) vc[PC].z -= alpha;
    else                         vc[PC].w -= alpha;
  }

  float a0 = 0.f, a1 = 0.f;                         // p_row = row . v
  #pragma unroll
  for (int j = 0; j < 4; ++j) {
    a0 = fmaf(r[4 * j + 0], vc[j].x, a0); a1 = fmaf(r[4 * j + 1], vc[j].y, a1);
    a0 = fmaf(r[4 * j + 2], vc[j].z, a0); a1 = fmaf(r[4 * j + 3], vc[j].w, a1);
  }
  float p_me = pair_sum(a0 + a1);
  if (h == 0) pbuf[row] = p_me;                     // stage raw p = C*v
  LDS_FENCE();

  float bv = beta * v_me;                           // auto-0 for frozen rows
  float bp = (row > K) ? beta * p_me : 0.0f;        // mask junk p

  // pass1: read p chunk; apply -bv*p[j] - bp*v[j]; accumulate G = v'p locally
  float g0 = 0.f, g1 = 0.f;
  #pragma unroll
  for (int j = 0; j < 4; ++j) {
    float4 pcx = *(const float4*)(pbuf + 16 * h + 4 * j);
    g0 = fmaf(vc[j].x, pcx.x, g0); g1 = fmaf(vc[j].y, pcx.y, g1);
    g0 = fmaf(vc[j].z, pcx.z, g0); g1 = fmaf(vc[j].w, pcx.w, g1);
    r[4 * j + 0] -= bv * pcx.x + bp * vc[j].x;
    r[4 * j + 1] -= bv * pcx.y + bp * vc[j].y;
    r[4 * j + 2] -= bv * pcx.z + bp * vc[j].z;
    r[4 * j + 3] -= bv * pcx.w + bp * vc[j].w;
  }
  float G  = pair_sum(g0 + g1);                     // junk killed by zero v
  float tv = (beta * beta * G) * v_me;              // auto-0 for frozen rows

  // pass2: + (b^2 G) v_row * v[j]
  #pragma unroll
  for (int j = 0; j < 4; ++j) {
    r[4 * j + 0] = fmaf(tv, vc[j].x, r[4 * j + 0]);
    r[4 * j + 1] = fmaf(tv, vc[j].y, r[4 * j + 1]);
    r[4 * j + 2] = fmaf(tv, vc[j].z, r[4 * j + 2]);
    r[4 * j + 3] = fmaf(tv, vc[j].w, r[4 * j + 3]);
  }

  if (row == K && h == HK) { de[K] = r[EK]; de[32 + K] = alpha; }
}

template<int K>
DEVINL void house_all(float (&r)[16], int row, int h,
                      float* vbuf, float* pbuf, float* de) {
  house_step<K>(r, row, h, vbuf, pbuf, de);
  if constexpr (K < 30) house_all<K + 1>(r, row, h, vbuf, pbuf, de);
}

// ================= fused kernel: 1 molecule per wave ========================
__global__ __launch_bounds__(256) void Correlation_85134841741354_kernel(
    const float* __restrict__ A, float* __restrict__ out, int M) {
  const int lane = threadIdx.x & 63;
  const int wave = threadIdx.x >> 6;
  const int q    = lane >> 4;            // Gram: 8-feature sub-chunk
  const int t    = lane & 15;            // Gram: MFMA row index
  const int row  = lane >> 1;            // house: row owned by this lane
  const int h    = lane & 1;             // house: column half
  const int mol  = blockIdx.x * 4 + wave;
  if (mol >= M) return;                  // M % 4 == 0

  // ONE C-tile per wave, stride 36 (float4-aligned). 4*1160*4B = 18.6 KB/block
  // -> LDS allows 8 blocks/CU; occupancy is VGPR-limited only. Tile reused as
  // Householder scratch after readback (wave-private, fence-ordered).
  __shared__ float ldsT[4][32 * 36 + 8];
  float* tq = &ldsT[wave][0];

  // ---------------- Gram via MFMA (hi/lo bf16 split) -------------------------
  {
    const float* Am = A + (size_t)mol * (32 * 128);
    f32x4 acc00 = {0.f, 0.f, 0.f, 0.f}, acc01 = {0.f, 0.f, 0.f, 0.f};
    f32x4 acc10 = {0.f, 0.f, 0.f, 0.f}, acc11 = {0.f, 0.f, 0.f, 0.f};
    #pragma unroll
    for (int c = 0; c < 4; ++c) {        // K chunks of 32 features
      const float* pr0 = Am + t * 128        + 32 * c + 8 * q;  // rows 0..15
      const float* pr1 = Am + (t + 16) * 128 + 32 * c + 8 * q;  // rows 16..31
      float4 fa0 = *(const float4*)(pr0);
      float4 fb0 = *(const float4*)(pr0 + 4);
      float4 fa1 = *(const float4*)(pr1);
      float4 fb1 = *(const float4*)(pr1 + 4);
      short8 h0, l0, h1, l1;
      cvt_hilo(fa0, fb0, h0, l0);
      cvt_hilo(fa1, fb1, h1, l1);
      // C = (hi+lo)(hi+lo)^T ~= hi hi^T + hi lo^T + lo hi^T  (drop lo lo^T)
      acc00 = mfma_bf16(h0, h0, acc00); acc00 = mfma_bf16(h0, l0, acc00); acc00 = mfma_bf16(l0, h0, acc00);
      acc01 = mfma_bf16(h0, h1, acc01); acc01 = mfma_bf16(h0, l1, acc01); acc01 = mfma_bf16(l0, h1, acc01);
      acc10 = mfma_bf16(h1, h0, acc10); acc10 = mfma_bf16(h1, l0, acc10); acc10 = mfma_bf16(l1, h0, acc10);
      acc11 = mfma_bf16(h1, h1, acc11); acc11 = mfma_bf16(h1, l1, acc11); acc11 = mfma_bf16(l1, h1, acc11);
    }
    // C/D layout: col = lane&15, row = (lane>>4)*4 + reg  [HW-verified]
    #pragma unroll
    for (int reg = 0; reg < 4; ++reg) {
      tq[(4 * q + reg) * 36 + t]           = acc00[reg];
      tq[(4 * q + reg) * 36 + 16 + t]      = acc01[reg];
      tq[(16 + 4 * q + reg) * 36 + t]      = acc10[reg];
      tq[(16 + 4 * q + reg) * 36 + 16 + t] = acc11[reg];
    }
  }
  LDS_FENCE();

  // readback in house layout: lane = 2*row+h reads C[row][16h..16h+15]
  float r[16];
  #pragma unroll
  for (int j = 0; j < 4; ++j) {
    float4 x = *(const float4*)(tq + row * 36 + 16 * h + 4 * j);
    r[4 * j + 0] = x.x; r[4 * j + 1] = x.y;
    r[4 * j + 2] = x.z; r[4 * j + 3] = x.w;
  }
  LDS_FENCE();   // order readback reads before scratch writes (aliased memory)

  // Householder scratch carved from the (now dead) tile; tiles are 1160 floats
  // apart == 8-bank stagger across the block's 4 waves.
  float* vbuf = tq;          // [0..31]  masked x
  float* pbuf = tq + 40;     // [0..31]  raw p
  float* de   = tq + 80;     // d[0..31] | e[0..31]

  // ---------------- Householder tridiagonalization ---------------------------
  house_all<0>(r, row, h, vbuf, pbuf, de);
  if (row == 31 && h == 1) { de[31] = r[15]; de[63] = 0.0f; }
  LDS_FENCE();

  // ---------------- tridiagonal to registers + local Gershgorin --------------
  float vd[32], ve[32];
  #pragma unroll
  for (int c = 0; c < 8; ++c) {
    float4 dc = *(const float4*)(de + 4 * c);
    float4 ec = *(const float4*)(de + 32 + 4 * c);
    vd[4 * c + 0] = dc.x; vd[4 * c + 1] = dc.y;
    vd[4 * c + 2] = dc.z; vd[4 * c + 3] = dc.w;
    ve[4 * c + 0] = ec.x; ve[4 * c + 1] = ec.y;
    ve[4 * c + 2] = ec.z; ve[4 * c + 3] = ec.w;
  }
  // Gershgorin bracket computed locally per lane (identical on all lanes).
  float glo = vd[0] - fabsf(ve[0]);
  float ghi = vd[0] + fabsf(ve[0]);
  #pragma unroll
  for (int i = 1; i < 32; ++i) {
    float rad = fabsf(ve[i]) + fabsf(ve[i - 1]);
    glo = fminf(glo, vd[i] - rad);
    ghi = fmaxf(ghi, vd[i] + rad);
  }
  float lo = fmaxf(glo - 1e-3f, 0.0f);   // C = A A' is PSD
  float hi = ghi + 1e-3f;

  #pragma unroll
  for (int i = 0; i < 32; ++i) ve[i] *= ve[i];

  // ---------------- Sturm bisection: 64 sigma points / round -----------------
  #pragma unroll
  for (int rr = 0; rr < 3; ++rr) {
    float stp = (hi - lo) * (1.0f / 65.0f);
    float sig = fmaf(stp, (float)(lane + 1), lo);
    float qq = vd[0] - sig;
    int cnt = (qq < 0.0f) ? 1 : 0;
    #pragma unroll
    for (int i = 1; i < 32; ++i) {
      float qs = (fabsf(qq) < 1e-12f) ? ((qq < 0.0f) ? -1e-12f : 1e-12f) : qq;
      qq = (vd[i] - sig) - ve[i - 1] * rcp_f(qs);
      cnt += (qq < 0.0f) ? 1 : 0;
    }
    unsigned long long m64 = __ballot(cnt >= 1);
    int b = (m64 == 0ull) ? 64 : (__ffsll((unsigned long long)m64) - 1);
    float nhi = (b == 64) ? hi : fmaf(stp, (float)(b + 1), lo);
    lo = fmaf(stp, (float)b, lo);
    hi = nhi;
  }

  if (lane == 0) out[mol] = 0.5f * (lo + hi);
}

extern "C" void kernel_launch(void* const* d_in, const int* in_sizes, int n_in,
                              void* d_out, int out_size, void* d_ws, size_t ws_size,
                              hipStream_t stream) {
  const float* A = (const float*)d_in[0];
  float* out = (float*)d_out;
  int n_atoms = in_sizes[1];          // 262144
  int M = n_atoms / 32;               // 8192 molecules
  int blocks = (M + 3) / 4;           // 4 molecules per 256-thread block
  hipLaunchKernelGGL(Correlation_85134841741354_kernel,
                     dim3(blocks), dim3(256), 0, stream, A, out, M);
}